// Round 2
// baseline (491.710 us; speedup 1.0000x reference)
//
#include <hip/hip_runtime.h>

typedef __attribute__((ext_vector_type(4)))  float    f32x4;
typedef __attribute__((ext_vector_type(16))) float    f32x16;
typedef __attribute__((ext_vector_type(8)))  _Float16 f16x8;

#define NB 2
#define NN 384
#define NO 4
#define NC 128
#define NK 64
#define MT 128     // m rows per workgroup (4 waves x 32)
#define NMT 3      // 384/128

// async global->LDS, 16B per lane, LDS dest = wave-uniform base + lane*16
__device__ __forceinline__ void async16(const float* g, float* l) {
    __builtin_amdgcn_global_load_lds((const __attribute__((address_space(1))) void*)g,
                                     (__attribute__((address_space(3))) void*)l, 16, 0, 0);
}

// ---------------------------------------------------------------------------
// Stage 1: per (b,o,mtile,split):  part[m,c] = sum_{n in split} sum_k
//          KB[b,m,n,o,k] * x[b,n,o,c] * Ws[k,c]
// Per-wave private async pipeline: NO barriers in the n-loop.
//   - A (32 rows x 64 k fp32, 8KB) staged per wave via global_load_lds into
//     layout [ku=k/4][m][4f32]; frags = 2x ds_read_b128 per kc.
//   - B operand built in registers: bfrag = f16(x[n,c]) * WsF16 (v_pk_mul_f16).
//   - sync = s_waitcnt vmcnt(8) only (per-wave double buffer).
// ---------------------------------------------------------------------------
__global__ __launch_bounds__(256, 2)
void sepconv_stage1(const float* __restrict__ KB, const float* __restrict__ X,
                    const float* __restrict__ Ws, float* __restrict__ part,
                    int ns)
{
    extern __shared__ float smem[];
    float* Abuf = smem;                 // [4 waves][2 bufs][2048 floats] = 64 KB
    float* xlds = smem + 4 * 2 * 2048;  // [ns][128]

    const int t    = threadIdx.x;
    const int lane = t & 63;
    const int w    = t >> 6;
    const int l31  = lane & 31;
    const int half = lane >> 5;

    const int wg    = blockIdx.x;
    const int b     = wg & 1;
    const int o     = (wg >> 1) & 3;
    const int mt    = (wg >> 3) % NMT;
    const int split = wg / 24;
    const int n0    = split * ns;

    // ---- Ws -> registers, f16, exact B-fragment order ----
    // element j of wsreg[cs][kc] = Ws[half*8 + kc*16 + j][cs*32 + l31]
    f16x8 wsreg[4][4];
    {
        const float* wp = Ws + half * 8 * NC + l31;
#pragma unroll
        for (int cs = 0; cs < 4; ++cs)
#pragma unroll
            for (int kc = 0; kc < 4; ++kc) {
                f16x8 v;
#pragma unroll
                for (int j = 0; j < 8; ++j)
                    v[j] = (_Float16)wp[(kc * 16 + j) * NC + cs * 32];
                wsreg[cs][kc] = v;
            }
    }

    // ---- x slice for this split -> LDS (coalesced) ----
    for (int idx = t; idx < ns * NC; idx += 256) {
        const int nl = idx >> 7, c = idx & 127;
        xlds[idx] = X[((b * NN + n0 + nl) * NO + o) * NC + c];
    }
    __syncthreads();   // also drains vmcnt to 0 before the manual-vmcnt pipeline

    // ---- per-lane global base for A staging ----
    // lane covers row m = l31 of this wave's subtile, k-offset half*4 floats
    const int mrow = mt * MT + w * 32 + l31;
    const float* gbase = KB + (size_t)(b * NN + mrow) * (NN * NO * NK)
                            + (size_t)n0 * (NO * NK) + o * NK + half * 4;
    float* const wbuf = Abuf + w * 2 * 2048;

    // stage one n-tile (8 issues of 1KB) into pipe buffer p
    auto stage = [&](int nl, int p) {
        const float* g = gbase + (size_t)nl * (NO * NK);
        float* l = wbuf + p * 2048;
#pragma unroll
        for (int i = 0; i < 8; ++i)
            async16(g + i * 8, l + i * 256);   // LDS unit u=i*64+lane -> [ku=2i+half][m=l31]
    };

    f32x16 acc[4];
#pragma unroll
    for (int cs = 0; cs < 4; ++cs)
#pragma unroll
        for (int r = 0; r < 16; ++r) acc[cs][r] = 0.f;

    stage(0, 0);
    stage(1, 1);

    for (int i = 0; i < ns; ++i) {
        if (i < ns - 1) __builtin_amdgcn_s_waitcnt(0x0F78);  // vmcnt <= 8: buf(i) ready
        else            __builtin_amdgcn_s_waitcnt(0x0F70);  // vmcnt 0
        __builtin_amdgcn_sched_barrier(0);

        // x broadcast values for this n, one per c-subtile
        f16x8 xh[4];
#pragma unroll
        for (int cs = 0; cs < 4; ++cs) {
            const _Float16 xv = (_Float16)xlds[i * NC + cs * 32 + l31];
            f16x8 s;
#pragma unroll
            for (int j = 0; j < 8; ++j) s[j] = xv;
            xh[cs] = s;
        }

        // A frags: [ku][m][4f32]; lane reads ku = half*2 + kc*4 and ku+1
        const float* ab = wbuf + (i & 1) * 2048 + half * 256 + l31 * 4;
#pragma unroll
        for (int kc = 0; kc < 4; ++kc) {
            const f32x4 a0 = *(const f32x4*)(ab + kc * 512);
            const f32x4 a1 = *(const f32x4*)(ab + kc * 512 + 128);
            f16x8 af;
#pragma unroll
            for (int j = 0; j < 4; ++j) { af[j] = (_Float16)a0[j]; af[4 + j] = (_Float16)a1[j]; }
#pragma unroll
            for (int cs = 0; cs < 4; ++cs) {
                const f16x8 bf = xh[cs] * wsreg[cs][kc];   // v_pk_mul_f16
                acc[cs] = __builtin_amdgcn_mfma_f32_32x32x16_f16(af, bf, acc[cs], 0, 0, 0);
            }
        }

        __builtin_amdgcn_sched_barrier(0);   // keep restage after frag reads
        if (i + 2 < ns) stage(i + 2, i & 1);
    }

    // ---- epilogue: fp32 partials [split][b][o][m][c] ----
    float* pb = part + ((size_t)(split * NB + b) * NO + o) * (NN * NC)
                     + (mt * MT + w * 32) * NC;
#pragma unroll
    for (int cs = 0; cs < 4; ++cs)
#pragma unroll
        for (int r = 0; r < 16; ++r) {
            const int ml = (r & 3) + 8 * (r >> 2) + 4 * half;  // C/D row map (m74/m101)
            pb[ml * NC + cs * 32 + l31] = acc[cs][r];
        }
}

// ---------------------------------------------------------------------------
// Stage 2: reduce splits, apply fiber/rot mixing + bias.
// out[b,m,p,c] = bias[c] + sum_o (sum_s part[s,b,o,m,c]) * rot[p,o,c]
// rot[p,o,c] = sum_k fiber[p,o,k] * Wr[k,c]
// ---------------------------------------------------------------------------
__global__ __launch_bounds__(256)
void sepconv_stage2(const float* __restrict__ part, const float* __restrict__ fiber,
                    const float* __restrict__ Wr, const float* __restrict__ bias,
                    float* __restrict__ out, int nsplit)
{
    const int bid = blockIdx.x;            // 0 .. B*N-1
    const int b = bid / NN;
    const int m = bid % NN;
    const int t = threadIdx.x;
    const int c = t & 127;
    const int g = t >> 7;                  // 0/1 -> p in {2g, 2g+1}

    float rot[8];
#pragma unroll
    for (int i = 0; i < 8; ++i) rot[i] = 0.f;
    for (int k = 0; k < NK; ++k) {
        const float wv = Wr[k * NC + c];
#pragma unroll
        for (int q = 0; q < 2; ++q)
#pragma unroll
            for (int oo = 0; oo < 4; ++oo)
                rot[q * 4 + oo] += fiber[((2 * g + q) * NO + oo) * NK + k] * wv;
    }

    float y1[4];
#pragma unroll
    for (int oo = 0; oo < 4; ++oo) {
        float s = 0.f;
        for (int sp = 0; sp < nsplit; ++sp)
            s += part[((size_t)(sp * NB + b) * NO + oo) * (NN * NC) + m * NC + c];
        y1[oo] = s;
    }

    const float bv = bias[c];
#pragma unroll
    for (int q = 0; q < 2; ++q) {
        float v = bv;
#pragma unroll
        for (int oo = 0; oo < 4; ++oo) v += y1[oo] * rot[q * 4 + oo];
        out[((b * NN + m) * NO + (2 * g + q)) * NC + c] = v;
    }
}

extern "C" void kernel_launch(void* const* d_in, const int* in_sizes, int n_in,
                              void* d_out, int out_size, void* d_ws, size_t ws_size,
                              hipStream_t stream)
{
    const float* X    = (const float*)d_in[0];
    const float* KB   = (const float*)d_in[1];
    const float* FB   = (const float*)d_in[2];
    const float* Ws   = (const float*)d_in[3];
    const float* Wr   = (const float*)d_in[4];
    const float* bias = (const float*)d_in[5];
    float* out  = (float*)d_out;
    float* part = (float*)d_ws;

    // one partial plane = B*O*N*C fp32 = 1.57 MB
    const size_t per = (size_t)NB * NO * NN * NC * sizeof(float);
    int nsplit = 16;                                   // grid 384, ns=24
    if (ws_size >= 32 * per) { /* could go 32, but 16 halves partial traffic */ }
    while (nsplit > 16 && (size_t)nsplit * per > ws_size) nsplit >>= 1;
    const int ns = NN / nsplit;

    const size_t lds = (4 * 2 * 2048 + (size_t)ns * NC) * sizeof(float); // 64KB + x slice

    sepconv_stage1<<<dim3(24 * nsplit), dim3(256), lds, stream>>>(KB, X, Ws, part, ns);
    sepconv_stage2<<<dim3(NB * NN), dim3(256), 0, stream>>>(part, FB, Wr, bias, out, nsplit);
}

// Round 4
// 451.790 us; speedup vs baseline: 1.0884x; 1.0884x over previous
//
#include <hip/hip_runtime.h>

typedef __attribute__((ext_vector_type(2)))  __fp16   pk16x2;  // cvt_pkrtz result type
typedef __attribute__((ext_vector_type(4)))  float    f32x4;
typedef __attribute__((ext_vector_type(16))) float    f32x16;
typedef __attribute__((ext_vector_type(8)))  _Float16 f16x8;

#define NB 2
#define NN 384
#define NO 4
#define NC 128
#define NK 64
#define MTW 32              // m rows per block
#define NSPLIT 16
#define NS (NN / NSPLIT)    // 24 source points per block
#define DEPTH 3
#define SLOTF 4096          // floats per A slot (32 rows x 128 floats)
#define SLOTB 16384         // bytes per A slot

union F16x8u { f16x8 v; pk16x2 h[4]; };

__device__ __forceinline__ void async16(const float* g, float* l) {
    __builtin_amdgcn_global_load_lds((const __attribute__((address_space(1))) void*)g,
                                     (__attribute__((address_space(3))) void*)l, 16, 0, 0);
}

// ---------------------------------------------------------------------------
// Stage 1: block = (b, o-pair p, 32-row m-tile, n-split).
//   part[2p+o, m, c] += sum_{n,k} KB[b,m,n,2p+o,k] * x[b,n,2p+o,c] * Ws[k,c]
// A staged via global_load_lds: 1 instr = 2 rows x 512B fully coalesced.
// 3-deep pipeline, raw s_barrier + manual vmcnt (no vmcnt(0) drain in loop).
// 16B rotation swizzle keeps frag ds_read_b128 bank-conflict-free.
// ---------------------------------------------------------------------------
__global__ __launch_bounds__(256, 2)
void sepconv_stage1(const float* __restrict__ KB, const float* __restrict__ X,
                    const float* __restrict__ Ws, float* __restrict__ part)
{
    extern __shared__ float smem[];
    float* Abuf = smem;                  // DEPTH * 4096 floats (48 KB)
    float* xlds = smem + DEPTH * SLOTF;  // NS * 256 floats (24 KB)

    const int t    = threadIdx.x;
    const int lane = t & 63;
    const int w    = t >> 6;
    const int l31  = lane & 31;
    const int lh   = lane >> 5;

    const int bid   = blockIdx.x;
    const int mt    = bid % 12;
    const int p     = (bid / 12) & 1;
    const int b     = (bid / 24) & 1;
    const int split = bid / 48;
    const int n0    = split * NS;
    const int cidx  = w * 32 + l31;

    // Ws -> f16 B-fragment registers (this wave's c-subtile)
    f16x8 wsreg[4];
    {
        const float* wp = Ws + (lh * 8) * NC + cidx;
#pragma unroll
        for (int kc = 0; kc < 4; ++kc) {
            f16x8 v;
#pragma unroll
            for (int j = 0; j < 8; ++j)
                v[j] = (_Float16)wp[(kc * 16 + j) * NC];
            wsreg[kc] = v;
        }
    }

    // x slice -> LDS (f32), layout [nl][o_local][c]
    for (int idx = t; idx < NS * 256; idx += 256) {
        const int nl = idx >> 8, rest = idx & 255;
        xlds[idx] = X[((b * NN + n0 + nl) * NO + 2 * p + (rest >> 7)) * NC + (rest & 127)];
    }
    __syncthreads();   // drains all counters; clean vmcnt accounting from here

    // per-lane A staging pointers: instr j covers rows 8w+2j(+lh), rotated chunks
    const float* gb[4];
#pragma unroll
    for (int j = 0; j < 4; ++j) {
        const int r = 8 * w + 2 * j + lh;
        const int m = mt * MTW + r;
        gb[j] = KB + ((size_t)(b * NN + m) * NN + n0) * (NO * NK)
                   + p * (2 * NK) + (((l31 + r) & 31) << 2);
    }

    // frag-read byte offsets within a slot (rotation-aware)
    int apos[2][4][2];
#pragma unroll
    for (int o = 0; o < 2; ++o)
#pragma unroll
        for (int kc = 0; kc < 4; ++kc) {
            const int q0 = o * 16 + kc * 4 + lh * 2;
            apos[o][kc][0] = l31 * 512 + ((q0     - l31) & 31) * 16;
            apos[o][kc][1] = l31 * 512 + ((q0 + 1 - l31) & 31) * 16;
        }

    f32x16 acc[2];
#pragma unroll
    for (int o = 0; o < 2; ++o)
#pragma unroll
        for (int r = 0; r < 16; ++r) acc[o][r] = 0.f;

    auto stage = [&](int nl, int slot) {
        float* lb = Abuf + slot * SLOTF + w * 1024;
#pragma unroll
        for (int j = 0; j < 4; ++j)
            async16(gb[j] + nl * (NO * NK), lb + j * 256);
    };

    auto compute = [&](int i, int slot) {
        const char* sb = (const char*)Abuf + slot * SLOTB;
#pragma unroll
        for (int o = 0; o < 2; ++o) {
            const _Float16 xv = (_Float16)xlds[i * 256 + o * 128 + cidx];
            f16x8 xh;
#pragma unroll
            for (int j = 0; j < 8; ++j) xh[j] = xv;
#pragma unroll
            for (int kc = 0; kc < 4; ++kc) {
                const f32x4 a0 = *(const f32x4*)(sb + apos[o][kc][0]);
                const f32x4 a1 = *(const f32x4*)(sb + apos[o][kc][1]);
                F16x8u af;
                af.h[0] = __builtin_amdgcn_cvt_pkrtz(a0[0], a0[1]);
                af.h[1] = __builtin_amdgcn_cvt_pkrtz(a0[2], a0[3]);
                af.h[2] = __builtin_amdgcn_cvt_pkrtz(a1[0], a1[1]);
                af.h[3] = __builtin_amdgcn_cvt_pkrtz(a1[2], a1[3]);
                const f16x8 bf = xh * wsreg[kc];
                acc[o] = __builtin_amdgcn_mfma_f32_32x32x16_f16(af.v, bf, acc[o], 0, 0, 0);
            }
        }
    };

    stage(0, 0);
    stage(1, 1);

    for (int ii = 0; ii + DEPTH < NS; ii += DEPTH) {
#pragma unroll
        for (int s = 0; s < DEPTH; ++s) {
            __builtin_amdgcn_s_waitcnt(0x0F74);   // vmcnt<=4: buf i done, i+1 in flight
            __builtin_amdgcn_s_barrier();         // raw: no vmcnt(0) drain
            __builtin_amdgcn_sched_barrier(0);
            stage(ii + s + 2, (s + 2) % 3);       // slot held buf i-1: all waves past it
            __builtin_amdgcn_sched_barrier(0);
            compute(ii + s, s);
        }
    }
    // tail: i = NS-3, NS-2, NS-1
    __builtin_amdgcn_s_waitcnt(0x0F74); __builtin_amdgcn_s_barrier();
    __builtin_amdgcn_sched_barrier(0);
    stage(NS - 1, 2);
    __builtin_amdgcn_sched_barrier(0);
    compute(NS - 3, 0);
    __builtin_amdgcn_s_waitcnt(0x0F74); __builtin_amdgcn_s_barrier();
    __builtin_amdgcn_sched_barrier(0);
    compute(NS - 2, 1);
    __builtin_amdgcn_s_waitcnt(0x0F70); __builtin_amdgcn_s_barrier();
    __builtin_amdgcn_sched_barrier(0);
    compute(NS - 1, 2);

    // epilogue: fp32 partials [split][b][o][m][c]
    float* pb = part + ((size_t)(split * NB + b) * NO + 2 * p) * (NN * NC)
                     + (size_t)(mt * MTW) * NC + cidx;
#pragma unroll
    for (int o = 0; o < 2; ++o)
#pragma unroll
        for (int r = 0; r < 16; ++r) {
            const int ml = (r & 3) + 8 * (r >> 2) + 4 * lh;   // C/D row map (m74/m101)
            pb[(size_t)o * NN * NC + ml * NC] = acc[o][r];
        }
}

// ---------------------------------------------------------------------------
// Stage 2: reduce splits, fiber/rot mixing + bias (unchanged from R2; passed).
// ---------------------------------------------------------------------------
__global__ __launch_bounds__(256)
void sepconv_stage2(const float* __restrict__ part, const float* __restrict__ fiber,
                    const float* __restrict__ Wr, const float* __restrict__ bias,
                    float* __restrict__ out, int nsplit)
{
    const int bid = blockIdx.x;
    const int b = bid / NN;
    const int m = bid % NN;
    const int t = threadIdx.x;
    const int c = t & 127;
    const int g = t >> 7;

    float rot[8];
#pragma unroll
    for (int i = 0; i < 8; ++i) rot[i] = 0.f;
    for (int k = 0; k < NK; ++k) {
        const float wv = Wr[k * NC + c];
#pragma unroll
        for (int q = 0; q < 2; ++q)
#pragma unroll
            for (int oo = 0; oo < 4; ++oo)
                rot[q * 4 + oo] += fiber[((2 * g + q) * NO + oo) * NK + k] * wv;
    }

    float y1[4];
#pragma unroll
    for (int oo = 0; oo < 4; ++oo) {
        float s = 0.f;
        for (int sp = 0; sp < nsplit; ++sp)
            s += part[((size_t)(sp * NB + b) * NO + oo) * (NN * NC) + m * NC + c];
        y1[oo] = s;
    }

    const float bv = bias[c];
#pragma unroll
    for (int q = 0; q < 2; ++q) {
        float v = bv;
#pragma unroll
        for (int oo = 0; oo < 4; ++oo) v += y1[oo] * rot[q * 4 + oo];
        out[((b * NN + m) * NO + (2 * g + q)) * NC + c] = v;
    }
}

extern "C" void kernel_launch(void* const* d_in, const int* in_sizes, int n_in,
                              void* d_out, int out_size, void* d_ws, size_t ws_size,
                              hipStream_t stream)
{
    const float* X    = (const float*)d_in[0];
    const float* KB   = (const float*)d_in[1];
    const float* FB   = (const float*)d_in[2];
    const float* Ws   = (const float*)d_in[3];
    const float* Wr   = (const float*)d_in[4];
    const float* bias = (const float*)d_in[5];
    float* out  = (float*)d_out;
    float* part = (float*)d_ws;   // 16 * 1.57 MB = 25 MB of fp32 partials

    const size_t lds = (DEPTH * SLOTF + NS * 256) * sizeof(float);  // 73728 B

    sepconv_stage1<<<dim3(12 * 2 * NB * NSPLIT), dim3(256), lds, stream>>>(KB, X, Ws, part);
    sepconv_stage2<<<dim3(NB * NN), dim3(256), 0, stream>>>(part, FB, Wr, bias, out, NSPLIT);
}